// Round 5
// baseline (525.308 us; speedup 1.0000x reference)
//
#include <hip/hip_runtime.h>
#include <hip/hip_bf16.h>

// B=16384 W=5 L=20 E=50 V=100000 C=128 H=4096 O=50
// ha  = bf16 [16384][256] (K-padded 250->256)
// wb  = bf16 [4096][256]  (fc1_w as [N][K])
// w2b = bf16 [64][4096]   (fc2_w padded to 64 rows)
// h   = bf16 [4096][4096] per chunk
// wbc = conv weights, B-fragment order for K=160 GEMM: [4 nt][5 ks][64 lane] short8
//
// conv as ONE GEMM: A'[l][k*50+i] = ce[l+k-1][i]  (K=150 pad 160, rows=words*20)
//                   B'[o][k*50+i] = conv_w[(o*50+i)*3+k]
// => conv_out = A'.B', no tap shift-add needed.

typedef __attribute__((ext_vector_type(8))) short short8;
typedef __attribute__((ext_vector_type(4))) float float4v;

__device__ inline short bf16b(float f) {
    __hip_bfloat16 h = __float2bfloat16(f);
    return *reinterpret_cast<short*>(&h);
}

// ---------------------------------------------------------------------------
__global__ void wb_kernel(const float* __restrict__ fc1_w,
                          __hip_bfloat16* __restrict__ wb) {
    int idx = blockIdx.x * 256 + threadIdx.x;     // n*256 + k
    int n = idx >> 8, k = idx & 255;
    wb[idx] = __float2bfloat16(k < 250 ? fc1_w[n * 250 + k] : 0.f);
}

// ---------------------------------------------------------------------------
__global__ void w2b_kernel(const float* __restrict__ fc2_w,
                           __hip_bfloat16* __restrict__ w2b) {
    int idx = blockIdx.x * 256 + threadIdx.x;     // n*4096 + k
    int n = idx >> 12;
    w2b[idx] = __float2bfloat16(n < 50 ? fc2_w[idx] : 0.f);
}

// ---------------------------------------------------------------------------
// conv weights -> B-fragment order, K=160 layout.
// wbc[((nt*5+s)*64+lane)*8+j] = B'[nt*16+(lane&15)][s*32+(lane>>4)*8+j]
// ---------------------------------------------------------------------------
__global__ void wbc_kernel(const float* __restrict__ conv_w,
                           short* __restrict__ wbc) {
    int idx = blockIdx.x * 256 + threadIdx.x;     // 0..1279
    if (idx >= 1280) return;
    int lane = idx & 63, t = idx >> 6;            // t = nt*5+s
    int nt = t / 5, s = t - nt * 5;
    int c = lane & 15, q = lane >> 4;
    int o = nt * 16 + c;
    short8 v;
    #pragma unroll
    for (int j = 0; j < 8; ++j) {
        int kc = s * 32 + q * 8 + j;
        int k = kc / 50, i = kc - k * 50;
        float f = (o < 50 && kc < 150) ? conv_w[(o * 50 + i) * 3 + k] : 0.f;
        v[j] = bf16b(f);
    }
    *(short8*)(wbc + (size_t)idx * 8) = v;
}

// ---------------------------------------------------------------------------
__global__ void haPad_kernel(__hip_bfloat16* __restrict__ ha) {
    int idx = blockIdx.x * 256 + threadIdx.x;     // b*6 + j
    int b = idx / 6, j = idx - b * 6;
    ha[b * 256 + 250 + j] = __float2bfloat16(0.f);
}

// ---------------------------------------------------------------------------
// conv MFMA kernel. Block = 4 words = 80 rows (5 m-tiles) x N=64 (4 n-tiles,
// one per wave) x K=160 (5 k-steps). A' in LDS [80][160] bf16 (25.6 KB),
// C maxpool via SEPARATE float LDS [80][68] (21.8 KB). 47.4 KB -> 3 blocks/CU.
// ---------------------------------------------------------------------------
#define CSTRIDE 160
__global__ __launch_bounds__(256) void conv_kernel(
    const int* __restrict__ x, const int* __restrict__ wci,
    const float* __restrict__ word_emb, const float* __restrict__ char_emb,
    const float* __restrict__ conv_b, const short* __restrict__ wbc,
    __hip_bfloat16* __restrict__ ha)
{
    __shared__ short As[80 * CSTRIDE];            // 25.6 KB
    __shared__ float Cs[80 * 68];                 // 21.76 KB (separate: no aliasing)

    const int tid  = threadIdx.x;
    const int lane = tid & 63;
    const int wv   = tid >> 6;
    const int gw0  = blockIdx.x * 4;

    // early prefetch of epilogue operands (long-latency word_emb gather)
    float we = 0.f, cbv = 0.f;
    int epi_w = 0, epi_o = 0;
    if (tid < 200) {
        epi_w = tid / 50; epi_o = tid - epi_w * 50;
        we  = word_emb[(size_t)x[gw0 + epi_w] * 50 + epi_o];
        cbv = conv_b[epi_o];
    }

    // ---- zero-fill A' holes: pad cols 150..159; (l=0,k=0); (l=19,k=2) ----
    for (int t = tid; t < 400; t += 256) {        // 80 rows x 5 short-pairs
        int r = t / 5, cp = t - (t / 5) * 5;
        *(int*)&As[r * CSTRIDE + 150 + cp * 2] = 0;
    }
    for (int t = tid; t < 200; t += 256) {        // edge bands, 2 x 4 words x 25 pairs
        int band = t / 100, u = t - band * 100;
        int w = u / 25, pr = u - w * 25;
        if (band == 0) *(int*)&As[(w * 20) * CSTRIDE + pr * 2] = 0;
        else           *(int*)&As[(w * 20 + 19) * CSTRIDE + 100 + pr * 2] = 0;
    }

    // ---- scatter ce rows into A' (each row feeds k=0,1,2 slots) ----
    for (int t = tid; t < 2000; t += 256) {       // 80 rows x 25 float2 chunks
        int r = t / 25, ic = t - r * 25;
        int w = r / 20, p = r - w * 20;
        int xid = x[gw0 + w];
        int cid = wci[xid * 20 + p];
        float2 v = *(const float2*)(char_emb + (size_t)cid * 50 + ic * 2);
        uint pk = (uint)(ushort)bf16b(v.x) | ((uint)(ushort)bf16b(v.y) << 16);
        int base = w * 20;
        *(uint*)&As[(base + p) * CSTRIDE + 50 + ic * 2] = pk;               // k=1,l=p
        if (p < 19) *(uint*)&As[(base + p + 1) * CSTRIDE + ic * 2] = pk;    // k=0,l=p+1
        if (p > 0)  *(uint*)&As[(base + p - 1) * CSTRIDE + 100 + ic * 2] = pk; // k=2,l=p-1
    }
    __syncthreads();

    // ---- MFMA: wave wv owns n-tile wv; 5 m-tiles x 5 k-steps ----
    short8 bv[5];
    #pragma unroll
    for (int s = 0; s < 5; ++s)
        bv[s] = *(const short8*)(wbc + (size_t)((wv * 5 + s) * 64 + lane) * 8);

    const int m = lane & 15, q = lane >> 4;
    float4v acc[5] = {};
    #pragma unroll
    for (int s = 0; s < 5; ++s) {
        #pragma unroll
        for (int mt = 0; mt < 5; ++mt) {
            short8 av = *(const short8*)&As[(mt * 16 + m) * CSTRIDE + s * 32 + q * 8];
            acc[mt] = __builtin_amdgcn_mfma_f32_16x16x32_bf16(av, bv[s], acc[mt], 0, 0, 0);
        }
    }

    // ---- C -> LDS (C layout: col=lane&15, row=q*4+r) ----
    {
        const int col = wv * 16 + m;
        #pragma unroll
        for (int mt = 0; mt < 5; ++mt)
            #pragma unroll
            for (int r = 0; r < 4; ++r)
                Cs[(mt * 16 + q * 4 + r) * 68 + col] = acc[mt][r];
    }
    __syncthreads();

    // ---- maxpool over l, + conv_b + word_emb, store bf16 ----
    if (tid < 200) {
        const float* g = Cs + epi_w * 20 * 68 + epi_o;
        float mx = -1e30f;
        #pragma unroll
        for (int l = 0; l < 20; ++l) mx = fmaxf(mx, g[l * 68]);
        float val = mx + cbv + we;
        int gw = gw0 + epi_w, b = gw / 5, wp = gw - b * 5;
        ha[b * 256 + wp * 50 + epi_o] = __float2bfloat16(val);
    }
}

// ---------------------------------------------------------------------------
// FC1 bf16 MFMA (unchanged, proven): 128x128 tile, 4 waves 2x2.
// ---------------------------------------------------------------------------
__global__ __launch_bounds__(256) void fc1_kernel(
    const __hip_bfloat16* __restrict__ ha, const __hip_bfloat16* __restrict__ wb,
    const float* __restrict__ fc1_b, __hip_bfloat16* __restrict__ h, int rowBase)
{
    __shared__ short8 As[512];
    __shared__ short8 Bs[512];
    const int tid  = threadIdx.x;
    const int lane = tid & 63;
    const int wv   = tid >> 6;
    const int wm = wv >> 1, wn = wv & 1;
    const int m0 = blockIdx.x * 128;
    const int n0 = blockIdx.y * 128;

    float4v acc[4][4] = {};

    for (int kt = 0; kt < 8; ++kt) {
        const int k0 = kt * 32;
        #pragma unroll
        for (int s = 0; s < 2; ++s) {
            int seg = s * 256 + tid;
            int mt = seg >> 6, l = seg & 63;
            int q = l >> 4, mm = l & 15;
            As[seg] = *(const short8*)(ha + (size_t)(rowBase + m0 + mt * 16 + mm) * 256 + k0 + q * 8);
            Bs[seg] = *(const short8*)(wb + (size_t)(n0 + mt * 16 + mm) * 256 + k0 + q * 8);
        }
        __syncthreads();
        short8 av[4], bv[4];
        #pragma unroll
        for (int t = 0; t < 4; ++t) {
            av[t] = As[(wm * 4 + t) * 64 + lane];
            bv[t] = Bs[(wn * 4 + t) * 64 + lane];
        }
        #pragma unroll
        for (int mt = 0; mt < 4; ++mt)
            #pragma unroll
            for (int nt = 0; nt < 4; ++nt)
                acc[mt][nt] = __builtin_amdgcn_mfma_f32_16x16x32_bf16(
                    av[mt], bv[nt], acc[mt][nt], 0, 0, 0);
        __syncthreads();
    }

    const int q = lane >> 4, m = lane & 15;
    #pragma unroll
    for (int mt = 0; mt < 4; ++mt) {
        #pragma unroll
        for (int nt = 0; nt < 4; ++nt) {
            const int col = n0 + wn * 64 + nt * 16 + m;
            const float bias = fc1_b[col];
            #pragma unroll
            for (int r = 0; r < 4; ++r) {
                const int row = m0 + wm * 64 + mt * 16 + q * 4 + r;
                float v = acc[mt][nt][r] + bias;
                float t = 1.f - 2.f / (__expf(2.f * v) + 1.f);
                h[(size_t)row * 4096 + col] = __float2bfloat16(t);
            }
        }
    }
}

// ---------------------------------------------------------------------------
// FC2 bf16 MFMA + fused softmax (exact R3 version, proven).
// ---------------------------------------------------------------------------
__global__ __launch_bounds__(256) void fc2_kernel(
    const __hip_bfloat16* __restrict__ h, const __hip_bfloat16* __restrict__ w2b,
    const float* __restrict__ fc2_b, float* __restrict__ out, int rowBase)
{
    __shared__ float part[4][32][64];
    const int tid  = threadIdx.x;
    const int lane = tid & 63;
    const int wv   = tid >> 6;
    const int rb = blockIdx.x * 32;
    const int m = lane & 15, q = lane >> 4;

    float4v acc[2][4] = {};
    const int kbase = wv * 1024;

    for (int s = 0; s < 32; ++s) {
        const int kk = kbase + s * 32 + q * 8;
        short8 av[2], bv[4];
        #pragma unroll
        for (int mt = 0; mt < 2; ++mt)
            av[mt] = *(const short8*)(h + (size_t)(rb + mt * 16 + m) * 4096 + kk);
        #pragma unroll
        for (int nt = 0; nt < 4; ++nt)
            bv[nt] = *(const short8*)(w2b + (size_t)(nt * 16 + m) * 4096 + kk);
        #pragma unroll
        for (int mt = 0; mt < 2; ++mt)
            #pragma unroll
            for (int nt = 0; nt < 4; ++nt)
                acc[mt][nt] = __builtin_amdgcn_mfma_f32_16x16x32_bf16(
                    av[mt], bv[nt], acc[mt][nt], 0, 0, 0);
    }

    #pragma unroll
    for (int mt = 0; mt < 2; ++mt)
        #pragma unroll
        for (int nt = 0; nt < 4; ++nt)
            #pragma unroll
            for (int r = 0; r < 4; ++r)
                part[wv][mt * 16 + q * 4 + r][nt * 16 + m] = acc[mt][nt][r];
    __syncthreads();

    #pragma unroll
    for (int t = 0; t < 8; ++t) {
        int idx = t * 256 + tid;
        int row = idx >> 6, col = idx & 63;
        float lg = part[0][row][col] + part[1][row][col]
                 + part[2][row][col] + part[3][row][col];
        part[0][row][col] = (col < 50) ? lg + fc2_b[col] : -1e30f;
    }
    __syncthreads();

    #pragma unroll
    for (int rr = 0; rr < 8; ++rr) {
        const int row = wv * 8 + rr;
        float v = part[0][row][lane];
        float mx = v;
        for (int off = 32; off > 0; off >>= 1) mx = fmaxf(mx, __shfl_xor(mx, off));
        float e = __expf(v - mx);
        float ssum = e;
        for (int off = 32; off > 0; off >>= 1) ssum += __shfl_xor(ssum, off);
        if (lane < 50)
            out[(size_t)(rowBase + rb + row) * 50 + lane] = e / ssum;
    }
}

// ---------------------------------------------------------------------------
extern "C" void kernel_launch(void* const* d_in, const int* in_sizes, int n_in,
                              void* d_out, int out_size, void* d_ws, size_t ws_size,
                              hipStream_t stream) {
    const int*   x        = (const int*)  d_in[0];
    const int*   wci      = (const int*)  d_in[1];
    const float* word_emb = (const float*)d_in[2];
    const float* char_emb = (const float*)d_in[3];
    const float* conv_w   = (const float*)d_in[4];
    const float* conv_b   = (const float*)d_in[5];
    const float* fc1_w    = (const float*)d_in[6];
    const float* fc1_b    = (const float*)d_in[7];
    const float* fc2_w    = (const float*)d_in[8];
    const float* fc2_b    = (const float*)d_in[9];
    float* out = (float*)d_out;

    char* ws = (char*)d_ws;
    __hip_bfloat16* ha  = (__hip_bfloat16*)ws;                                  // 8 MB
    __hip_bfloat16* wb  = (__hip_bfloat16*)(ws + ((size_t)8 << 20));            // 2 MB
    __hip_bfloat16* w2b = (__hip_bfloat16*)(ws + ((size_t)10 << 20));           // 0.5 MB
    __hip_bfloat16* h   = (__hip_bfloat16*)(ws + ((size_t)10 << 20) + ((size_t)512 << 10)); // 32 MB
    short*          wbcp = (short*)(ws + ((size_t)42 << 20) + ((size_t)512 << 10));         // 20 KB

    wb_kernel<<<4096, 256, 0, stream>>>(fc1_w, wb);
    w2b_kernel<<<1024, 256, 0, stream>>>(fc2_w, w2b);
    wbc_kernel<<<5, 256, 0, stream>>>(conv_w, wbcp);
    haPad_kernel<<<384, 256, 0, stream>>>(ha);
    conv_kernel<<<20480, 256, 0, stream>>>(x, wci, word_emb, char_emb,
                                           conv_b, wbcp, ha);
    for (int c = 0; c < 4; ++c) {
        const int rowBase = c * 4096;
        fc1_kernel<<<dim3(32, 32), 256, 0, stream>>>(ha, wb, fc1_b, h, rowBase);
        fc2_kernel<<<128, 256, 0, stream>>>(h, w2b, fc2_b, out, rowBase);
    }
}

// Round 6
// 464.575 us; speedup vs baseline: 1.1307x; 1.1307x over previous
//
#include <hip/hip_runtime.h>
#include <hip/hip_bf16.h>

// B=16384 W=5 L=20 E=50 V=100000 C=128 H=4096 O=50
// ha  = bf16 [16384][256] (K-padded 250->256)
// wb  = bf16 [4096][256]  (fc1_w as [N][K])
// w2b = bf16 [64][4096]   (fc2_w padded to 64 rows)
// h   = bf16 [4096][4096] per chunk
// wbc = conv weights, B-fragment order for K=160 GEMM: [4 nt][5 ks][64 lane] short8
//
// conv as ONE GEMM: A'[l][k*50+i] = ce[l+k-1][i]  (K=150 pad 160, rows=words*20)
//                   B'[o][k*50+i] = conv_w[(o*50+i)*3+k]
// => conv_out = A'.B', no tap shift-add needed.

typedef __attribute__((ext_vector_type(8))) short short8;
typedef __attribute__((ext_vector_type(4))) float float4v;

__device__ inline short bf16b(float f) {
    __hip_bfloat16 h = __float2bfloat16(f);
    return *reinterpret_cast<short*>(&h);
}

// ---------------------------------------------------------------------------
__global__ void wb_kernel(const float* __restrict__ fc1_w,
                          __hip_bfloat16* __restrict__ wb) {
    int idx = blockIdx.x * 256 + threadIdx.x;     // n*256 + k
    int n = idx >> 8, k = idx & 255;
    wb[idx] = __float2bfloat16(k < 250 ? fc1_w[n * 250 + k] : 0.f);
}

// ---------------------------------------------------------------------------
__global__ void w2b_kernel(const float* __restrict__ fc2_w,
                           __hip_bfloat16* __restrict__ w2b) {
    int idx = blockIdx.x * 256 + threadIdx.x;     // n*4096 + k
    int n = idx >> 12;
    w2b[idx] = __float2bfloat16(n < 50 ? fc2_w[idx] : 0.f);
}

// ---------------------------------------------------------------------------
// conv weights -> B-fragment order, K=160 layout.
// wbc[((nt*5+s)*64+lane)*8+j] = B'[nt*16+(lane&15)][s*32+(lane>>4)*8+j]
// ---------------------------------------------------------------------------
__global__ void wbc_kernel(const float* __restrict__ conv_w,
                           short* __restrict__ wbc) {
    int idx = blockIdx.x * 256 + threadIdx.x;     // 0..1279
    if (idx >= 1280) return;
    int lane = idx & 63, t = idx >> 6;            // t = nt*5+s
    int nt = t / 5, s = t - nt * 5;
    int c = lane & 15, q = lane >> 4;
    int o = nt * 16 + c;
    short8 v;
    #pragma unroll
    for (int j = 0; j < 8; ++j) {
        int kc = s * 32 + q * 8 + j;
        int k = kc / 50, i = kc - k * 50;
        float f = (o < 50 && kc < 150) ? conv_w[(o * 50 + i) * 3 + k] : 0.f;
        v[j] = bf16b(f);
    }
    *(short8*)(wbc + (size_t)idx * 8) = v;
}

// ---------------------------------------------------------------------------
__global__ void haPad_kernel(__hip_bfloat16* __restrict__ ha) {
    int idx = blockIdx.x * 256 + threadIdx.x;     // b*6 + j
    int b = idx / 6, j = idx - b * 6;
    ha[b * 256 + 250 + j] = __float2bfloat16(0.f);
}

// ---------------------------------------------------------------------------
// conv MFMA kernel. Block = 4 words = 80 rows (5 m-tiles) x N=64 (4 n-tiles,
// one per wave) x K=160 (5 k-steps).
// A' LDS [80][168] bf16 (stride-padded: 84 dwords, period-8 bank spread).
// Cs LDS [80][72] fp32 (stride 72 -> exactly 2-way on C-write = free).
// cids staged to LDS first: kills the x->wci->char_emb dependent chain.
// ---------------------------------------------------------------------------
#define CSTRIDE 168
#define GSTRIDE 72
__global__ __launch_bounds__(256) void conv_kernel(
    const int* __restrict__ x, const int* __restrict__ wci,
    const float* __restrict__ word_emb, const float* __restrict__ char_emb,
    const float* __restrict__ conv_b, const short* __restrict__ wbc,
    __hip_bfloat16* __restrict__ ha)
{
    __shared__ short As[80 * CSTRIDE];            // 26.25 KB
    __shared__ float Cs[80 * GSTRIDE];            // 22.5 KB
    __shared__ int   cids[80];                    // premultiplied by 50

    const int tid  = threadIdx.x;
    const int lane = tid & 63;
    const int wv   = tid >> 6;
    const int gw0  = blockIdx.x * 4;

    // ---- stage cids: 80 parallel loads, one latency for the whole block ----
    if (tid < 80) {
        int w = tid / 20, p = tid - w * 20;
        int xid = x[gw0 + w];
        cids[tid] = wci[xid * 20 + p] * 50;
    }

    // epilogue operand prefetch (independent x->word_emb chain, overlaps all)
    float we = 0.f, cbv = 0.f;
    int epi_w = 0, epi_o = 0;
    if (tid < 200) {
        epi_w = tid / 50; epi_o = tid - epi_w * 50;
        we  = word_emb[(size_t)x[gw0 + epi_w] * 50 + epi_o];
        cbv = conv_b[epi_o];
    }

    // ---- zero-fill A' holes: pad cols 150..159; (l=0,k=0); (l=19,k=2) ----
    for (int t = tid; t < 400; t += 256) {        // 80 rows x 5 short-pairs
        int r = t / 5, cp = t - (t / 5) * 5;
        *(int*)&As[r * CSTRIDE + 150 + cp * 2] = 0;
    }
    for (int t = tid; t < 200; t += 256) {        // edge bands
        int band = t / 100, u = t - band * 100;
        int w = u / 25, pr = u - w * 25;
        if (band == 0) *(int*)&As[(w * 20) * CSTRIDE + pr * 2] = 0;
        else           *(int*)&As[(w * 20 + 19) * CSTRIDE + 100 + pr * 2] = 0;
    }
    __syncthreads();   // cids visible

    // ---- gather ce -> scatter into A'. Uniform 8-trip unrolled: all loads
    //      independent and issued together. 250 threads x 8 = 80 rows x 25.
    if (tid < 250) {
        const int rb0 = tid / 25, ic0 = tid - (tid / 25) * 25;
        #pragma unroll
        for (int it = 0; it < 8; ++it) {
            const int r = it * 10 + rb0;          // 0..79
            const int w = r / 20, p = r - (r / 20) * 20;
            float2 v = *(const float2*)(char_emb + cids[r] + ic0 * 2);
            uint pk = (uint)(ushort)bf16b(v.x) | ((uint)(ushort)bf16b(v.y) << 16);
            const int base = w * 20;
            *(uint*)&As[(base + p) * CSTRIDE + 50 + ic0 * 2] = pk;               // k=1,l=p
            if (p < 19) *(uint*)&As[(base + p + 1) * CSTRIDE + ic0 * 2] = pk;    // k=0,l=p+1
            if (p > 0)  *(uint*)&As[(base + p - 1) * CSTRIDE + 100 + ic0 * 2] = pk; // k=2,l=p-1
        }
    }
    __syncthreads();

    // ---- MFMA: wave wv owns n-tile wv; 5 m-tiles x 5 k-steps ----
    short8 bv[5];
    #pragma unroll
    for (int s = 0; s < 5; ++s)
        bv[s] = *(const short8*)(wbc + (size_t)((wv * 5 + s) * 64 + lane) * 8);

    const int m = lane & 15, q = lane >> 4;
    float4v acc[5] = {};
    #pragma unroll
    for (int s = 0; s < 5; ++s) {
        #pragma unroll
        for (int mt = 0; mt < 5; ++mt) {
            short8 av = *(const short8*)&As[(mt * 16 + m) * CSTRIDE + s * 32 + q * 8];
            acc[mt] = __builtin_amdgcn_mfma_f32_16x16x32_bf16(av, bv[s], acc[mt], 0, 0, 0);
        }
    }

    // ---- C -> LDS (C layout: col=lane&15, row=q*4+r) ----
    {
        const int col = wv * 16 + m;
        #pragma unroll
        for (int mt = 0; mt < 5; ++mt)
            #pragma unroll
            for (int r = 0; r < 4; ++r)
                Cs[(mt * 16 + q * 4 + r) * GSTRIDE + col] = acc[mt][r];
    }
    __syncthreads();

    // ---- maxpool over l, + conv_b + word_emb, store bf16 ----
    if (tid < 200) {
        const float* g = Cs + epi_w * 20 * GSTRIDE + epi_o;
        float mx = -1e30f;
        #pragma unroll
        for (int l = 0; l < 20; ++l) mx = fmaxf(mx, g[l * GSTRIDE]);
        float val = mx + cbv + we;
        int gw = gw0 + epi_w, b = gw / 5, wp = gw - b * 5;
        ha[b * 256 + wp * 50 + epi_o] = __float2bfloat16(val);
    }
}

// ---------------------------------------------------------------------------
// FC1 bf16 MFMA (unchanged, proven): 128x128 tile, 4 waves 2x2.
// ---------------------------------------------------------------------------
__global__ __launch_bounds__(256) void fc1_kernel(
    const __hip_bfloat16* __restrict__ ha, const __hip_bfloat16* __restrict__ wb,
    const float* __restrict__ fc1_b, __hip_bfloat16* __restrict__ h, int rowBase)
{
    __shared__ short8 As[512];
    __shared__ short8 Bs[512];
    const int tid  = threadIdx.x;
    const int lane = tid & 63;
    const int wv   = tid >> 6;
    const int wm = wv >> 1, wn = wv & 1;
    const int m0 = blockIdx.x * 128;
    const int n0 = blockIdx.y * 128;

    float4v acc[4][4] = {};

    for (int kt = 0; kt < 8; ++kt) {
        const int k0 = kt * 32;
        #pragma unroll
        for (int s = 0; s < 2; ++s) {
            int seg = s * 256 + tid;
            int mt = seg >> 6, l = seg & 63;
            int q = l >> 4, mm = l & 15;
            As[seg] = *(const short8*)(ha + (size_t)(rowBase + m0 + mt * 16 + mm) * 256 + k0 + q * 8);
            Bs[seg] = *(const short8*)(wb + (size_t)(n0 + mt * 16 + mm) * 256 + k0 + q * 8);
        }
        __syncthreads();
        short8 av[4], bv[4];
        #pragma unroll
        for (int t = 0; t < 4; ++t) {
            av[t] = As[(wm * 4 + t) * 64 + lane];
            bv[t] = Bs[(wn * 4 + t) * 64 + lane];
        }
        #pragma unroll
        for (int mt = 0; mt < 4; ++mt)
            #pragma unroll
            for (int nt = 0; nt < 4; ++nt)
                acc[mt][nt] = __builtin_amdgcn_mfma_f32_16x16x32_bf16(
                    av[mt], bv[nt], acc[mt][nt], 0, 0, 0);
        __syncthreads();
    }

    const int q = lane >> 4, m = lane & 15;
    #pragma unroll
    for (int mt = 0; mt < 4; ++mt) {
        #pragma unroll
        for (int nt = 0; nt < 4; ++nt) {
            const int col = n0 + wn * 64 + nt * 16 + m;
            const float bias = fc1_b[col];
            #pragma unroll
            for (int r = 0; r < 4; ++r) {
                const int row = m0 + wm * 64 + mt * 16 + q * 4 + r;
                float v = acc[mt][nt][r] + bias;
                float t = 1.f - 2.f / (__expf(2.f * v) + 1.f);
                h[(size_t)row * 4096 + col] = __float2bfloat16(t);
            }
        }
    }
}

// ---------------------------------------------------------------------------
// FC2 bf16 MFMA + fused softmax (exact R3/R5 version, proven).
// ---------------------------------------------------------------------------
__global__ __launch_bounds__(256) void fc2_kernel(
    const __hip_bfloat16* __restrict__ h, const __hip_bfloat16* __restrict__ w2b,
    const float* __restrict__ fc2_b, float* __restrict__ out, int rowBase)
{
    __shared__ float part[4][32][64];
    const int tid  = threadIdx.x;
    const int lane = tid & 63;
    const int wv   = tid >> 6;
    const int rb = blockIdx.x * 32;
    const int m = lane & 15, q = lane >> 4;

    float4v acc[2][4] = {};
    const int kbase = wv * 1024;

    for (int s = 0; s < 32; ++s) {
        const int kk = kbase + s * 32 + q * 8;
        short8 av[2], bv[4];
        #pragma unroll
        for (int mt = 0; mt < 2; ++mt)
            av[mt] = *(const short8*)(h + (size_t)(rb + mt * 16 + m) * 4096 + kk);
        #pragma unroll
        for (int nt = 0; nt < 4; ++nt)
            bv[nt] = *(const short8*)(w2b + (size_t)(nt * 16 + m) * 4096 + kk);
        #pragma unroll
        for (int mt = 0; mt < 2; ++mt)
            #pragma unroll
            for (int nt = 0; nt < 4; ++nt)
                acc[mt][nt] = __builtin_amdgcn_mfma_f32_16x16x32_bf16(
                    av[mt], bv[nt], acc[mt][nt], 0, 0, 0);
    }

    #pragma unroll
    for (int mt = 0; mt < 2; ++mt)
        #pragma unroll
        for (int nt = 0; nt < 4; ++nt)
            #pragma unroll
            for (int r = 0; r < 4; ++r)
                part[wv][mt * 16 + q * 4 + r][nt * 16 + m] = acc[mt][nt][r];
    __syncthreads();

    #pragma unroll
    for (int t = 0; t < 8; ++t) {
        int idx = t * 256 + tid;
        int row = idx >> 6, col = idx & 63;
        float lg = part[0][row][col] + part[1][row][col]
                 + part[2][row][col] + part[3][row][col];
        part[0][row][col] = (col < 50) ? lg + fc2_b[col] : -1e30f;
    }
    __syncthreads();

    #pragma unroll
    for (int rr = 0; rr < 8; ++rr) {
        const int row = wv * 8 + rr;
        float v = part[0][row][lane];
        float mx = v;
        for (int off = 32; off > 0; off >>= 1) mx = fmaxf(mx, __shfl_xor(mx, off));
        float e = __expf(v - mx);
        float ssum = e;
        for (int off = 32; off > 0; off >>= 1) ssum += __shfl_xor(ssum, off);
        if (lane < 50)
            out[(size_t)(rowBase + rb + row) * 50 + lane] = e / ssum;
    }
}

// ---------------------------------------------------------------------------
extern "C" void kernel_launch(void* const* d_in, const int* in_sizes, int n_in,
                              void* d_out, int out_size, void* d_ws, size_t ws_size,
                              hipStream_t stream) {
    const int*   x        = (const int*)  d_in[0];
    const int*   wci      = (const int*)  d_in[1];
    const float* word_emb = (const float*)d_in[2];
    const float* char_emb = (const float*)d_in[3];
    const float* conv_w   = (const float*)d_in[4];
    const float* conv_b   = (const float*)d_in[5];
    const float* fc1_w    = (const float*)d_in[6];
    const float* fc1_b    = (const float*)d_in[7];
    const float* fc2_w    = (const float*)d_in[8];
    const float* fc2_b    = (const float*)d_in[9];
    float* out = (float*)d_out;

    char* ws = (char*)d_ws;
    __hip_bfloat16* ha  = (__hip_bfloat16*)ws;                                  // 8 MB
    __hip_bfloat16* wb  = (__hip_bfloat16*)(ws + ((size_t)8 << 20));            // 2 MB
    __hip_bfloat16* w2b = (__hip_bfloat16*)(ws + ((size_t)10 << 20));           // 0.5 MB
    __hip_bfloat16* h   = (__hip_bfloat16*)(ws + ((size_t)10 << 20) + ((size_t)512 << 10)); // 32 MB
    short*          wbcp = (short*)(ws + ((size_t)42 << 20) + ((size_t)512 << 10));         // 20 KB

    wb_kernel<<<4096, 256, 0, stream>>>(fc1_w, wb);
    w2b_kernel<<<1024, 256, 0, stream>>>(fc2_w, w2b);
    wbc_kernel<<<5, 256, 0, stream>>>(conv_w, wbcp);
    haPad_kernel<<<384, 256, 0, stream>>>(ha);
    conv_kernel<<<20480, 256, 0, stream>>>(x, wci, word_emb, char_emb,
                                           conv_b, wbcp, ha);
    for (int c = 0; c < 4; ++c) {
        const int rowBase = c * 4096;
        fc1_kernel<<<dim3(32, 32), 256, 0, stream>>>(ha, wb, fc1_b, h, rowBase);
        fc2_kernel<<<128, 256, 0, stream>>>(h, w2b, fc2_b, out, rowBase);
    }
}

// Round 7
// 386.356 us; speedup vs baseline: 1.3596x; 1.2025x over previous
//
#include <hip/hip_runtime.h>
#include <hip/hip_bf16.h>

// B=16384 W=5 L=20 E=50 V=100000 C=128 H=4096 O=50
// ha  = bf16 [16384][256] (K-padded 250->256)
// wb  = bf16 [4096][256]  (fc1_w as [N][K])
// w2b = bf16 [64][4096]   (fc2_w padded to 64 rows)
// h   = bf16 [4096][4096] per chunk
// gt  = fp32 [128][156]: gt[c*156 + k*52 + o] = sum_i char_emb[c][i]*conv_w[o][i][k]
//
// conv identity (only 128 distinct chars!):
//   conv[l][o] = gt[cid[l-1]][0][o] + gt[cid[l]][1][o] + gt[cid[l+1]][2][o]
// (k=0 term absent at l=0, k=2 term absent at l=19). 24.6 GF GEMM -> 246 MF adds.

typedef __attribute__((ext_vector_type(8))) short short8;
typedef __attribute__((ext_vector_type(4))) float float4v;

__device__ inline short bf16b(float f) {
    __hip_bfloat16 h = __float2bfloat16(f);
    return *reinterpret_cast<short*>(&h);
}
__device__ inline uint packbf2(float a, float b) {
    return (uint)(ushort)bf16b(a) | ((uint)(ushort)bf16b(b) << 16);
}

// ---------------------------------------------------------------------------
__global__ void wb_kernel(const float* __restrict__ fc1_w,
                          __hip_bfloat16* __restrict__ wb) {
    int idx = blockIdx.x * 256 + threadIdx.x;     // n*256 + k
    int n = idx >> 8, k = idx & 255;
    wb[idx] = __float2bfloat16(k < 250 ? fc1_w[n * 250 + k] : 0.f);
}

// ---------------------------------------------------------------------------
__global__ void w2b_kernel(const float* __restrict__ fc2_w,
                           __hip_bfloat16* __restrict__ w2b) {
    int idx = blockIdx.x * 256 + threadIdx.x;     // n*4096 + k
    int n = idx >> 12;
    w2b[idx] = __float2bfloat16(n < 50 ? fc2_w[idx] : 0.f);
}

// ---------------------------------------------------------------------------
// gt[c*156 + kk*52 + o] = sum_i char_emb[c*50+i] * conv_w[(o*50+i)*3+kk]
// 19200 outputs, 50 MACs each. fp32 throughout.
// ---------------------------------------------------------------------------
__global__ void gt_kernel(const float* __restrict__ char_emb,
                          const float* __restrict__ conv_w,
                          float* __restrict__ gt) {
    int idx = blockIdx.x * 256 + threadIdx.x;     // < 19200
    if (idx >= 19200) return;
    int c = idx / 150, rem = idx - c * 150;
    int kk = rem / 50, o = rem - kk * 50;
    const float* ce = char_emb + c * 50;
    const float* w  = conv_w + o * 150 + kk;
    float s = 0.f;
    #pragma unroll 10
    for (int i = 0; i < 50; ++i) s += ce[i] * w[i * 3];
    gt[c * 156 + kk * 52 + o] = s;
}

// ---------------------------------------------------------------------------
__global__ void haPad_kernel(__hip_bfloat16* __restrict__ ha) {
    int idx = blockIdx.x * 256 + threadIdx.x;     // b*6 + j
    int b = idx / 6, j = idx - b * 6;
    ha[b * 256 + 250 + j] = __float2bfloat16(0.f);
}

// ---------------------------------------------------------------------------
// conv via table lookup. Block = 512 thr (8 waves) = 32 words.
// Wave: 4 words x 16 lanes; lane t = float4 o-chunk (t=0..12 used, 13..15 dup t=12).
// Gtab staged to LDS (79.9 KB); cids packed 4-per-uint (640 B). 2 blocks/CU.
// ---------------------------------------------------------------------------
__global__ __launch_bounds__(512) void conv_kernel(
    const int* __restrict__ x, const int* __restrict__ wci,
    const float* __restrict__ word_emb, const float* __restrict__ conv_b,
    const float* __restrict__ gt, __hip_bfloat16* __restrict__ ha)
{
    __shared__ float Gs[19968];       // 79,872 B
    __shared__ uint  cpack[160];      // 32 words x 20 cids as bytes (5 uints/word)
    __shared__ int   xs[32];

    const int tid = threadIdx.x;
    const int gw0 = blockIdx.x * 32;

    // x loads first (longest dependent chain), overlapped with Gs staging
    int xr = 0;
    if (tid < 32) xr = x[gw0 + tid];

    #pragma unroll
    for (int t = 0; t < 39; ++t)
        Gs[t * 512 + tid] = gt[t * 512 + tid];

    if (tid < 32) {
        const int* crow = wci + xr * 20;
        int cid[20];
        #pragma unroll
        for (int p = 0; p < 20; ++p) cid[p] = crow[p];
        #pragma unroll
        for (int u = 0; u < 5; ++u)
            cpack[tid * 5 + u] = (uint)cid[u * 4] | ((uint)cid[u * 4 + 1] << 8)
                               | ((uint)cid[u * 4 + 2] << 16) | ((uint)cid[u * 4 + 3] << 24);
        xs[tid] = xr;
    }
    __syncthreads();

    const int lane = tid & 63;
    const int wv   = tid >> 6;
    const int t    = lane & 15;
    const int w    = lane >> 4;
    const int tc   = (t < 13) ? t : 12;      // lanes 13..15 duplicate 12 (broadcast)
    const int widx = wv * 4 + w;             // block-local word 0..31

    // unpack this word's 20 cids -> premultiplied row offsets
    uint cw[5];
    #pragma unroll
    for (int u = 0; u < 5; ++u) cw[u] = cpack[widx * 5 + u];
    int ca[20];
    #pragma unroll
    for (int p = 0; p < 20; ++p)
        ca[p] = (int)((cw[p >> 2] >> ((p & 3) * 8)) & 0xFF) * 156;

    const int tc4 = tc * 4;
    float4 mx;
    {   // l = 0: k=1 (cid[0]) + k=2 (cid[1])
        float4 v = *(const float4*)&Gs[ca[0] + 52 + tc4];
        float4 u = *(const float4*)&Gs[ca[1] + 104 + tc4];
        mx.x = v.x + u.x; mx.y = v.y + u.y; mx.z = v.z + u.z; mx.w = v.w + u.w;
    }
    #pragma unroll
    for (int l = 1; l < 19; ++l) {
        float4 v = *(const float4*)&Gs[ca[l] + 52 + tc4];
        float4 a = *(const float4*)&Gs[ca[l - 1] + tc4];
        float4 b = *(const float4*)&Gs[ca[l + 1] + 104 + tc4];
        float vx = v.x + a.x + b.x, vy = v.y + a.y + b.y;
        float vz = v.z + a.z + b.z, vw = v.w + a.w + b.w;
        mx.x = fmaxf(mx.x, vx); mx.y = fmaxf(mx.y, vy);
        mx.z = fmaxf(mx.z, vz); mx.w = fmaxf(mx.w, vw);
    }
    {   // l = 19: k=0 (cid[18]) + k=1 (cid[19])
        float4 v = *(const float4*)&Gs[ca[19] + 52 + tc4];
        float4 a = *(const float4*)&Gs[ca[18] + tc4];
        mx.x = fmaxf(mx.x, v.x + a.x); mx.y = fmaxf(mx.y, v.y + a.y);
        mx.z = fmaxf(mx.z, v.z + a.z); mx.w = fmaxf(mx.w, v.w + a.w);
    }

    // epilogue: + conv_b + word_emb, store bf16 (guarded: o<50)
    const int xid = xs[widx];
    const float* wer = word_emb + (size_t)xid * 50 + tc4;
    float2 wea = *(const float2*)wer;
    float2 web = make_float2(0.f, 0.f);
    float2 cba = *(const float2*)(conv_b + tc4);
    float2 cbb = make_float2(0.f, 0.f);
    if (tc < 12) {
        web = *(const float2*)(wer + 2);
        cbb = *(const float2*)(conv_b + tc4 + 2);
    }
    const int gw = gw0 + widx, b = gw / 5, wp = gw - b * 5;
    __hip_bfloat16* dst = ha + b * 256 + wp * 50 + tc4;
    uint lo = packbf2(mx.x + cba.x + wea.x, mx.y + cba.y + wea.y);
    if (t < 12) {
        uint hi = packbf2(mx.z + cbb.x + web.x, mx.w + cbb.y + web.y);
        *(uint*)dst = lo;
        *((uint*)dst + 1) = hi;
    } else if (t == 12) {
        *(uint*)dst = lo;
    }
}

// ---------------------------------------------------------------------------
// FC1 bf16 MFMA (unchanged, proven): 128x128 tile, 4 waves 2x2.
// ---------------------------------------------------------------------------
__global__ __launch_bounds__(256) void fc1_kernel(
    const __hip_bfloat16* __restrict__ ha, const __hip_bfloat16* __restrict__ wb,
    const float* __restrict__ fc1_b, __hip_bfloat16* __restrict__ h, int rowBase)
{
    __shared__ short8 As[512];
    __shared__ short8 Bs[512];
    const int tid  = threadIdx.x;
    const int lane = tid & 63;
    const int wv   = tid >> 6;
    const int wm = wv >> 1, wn = wv & 1;
    const int m0 = blockIdx.x * 128;
    const int n0 = blockIdx.y * 128;

    float4v acc[4][4] = {};

    for (int kt = 0; kt < 8; ++kt) {
        const int k0 = kt * 32;
        #pragma unroll
        for (int s = 0; s < 2; ++s) {
            int seg = s * 256 + tid;
            int mt = seg >> 6, l = seg & 63;
            int q = l >> 4, mm = l & 15;
            As[seg] = *(const short8*)(ha + (size_t)(rowBase + m0 + mt * 16 + mm) * 256 + k0 + q * 8);
            Bs[seg] = *(const short8*)(wb + (size_t)(n0 + mt * 16 + mm) * 256 + k0 + q * 8);
        }
        __syncthreads();
        short8 av[4], bv[4];
        #pragma unroll
        for (int t = 0; t < 4; ++t) {
            av[t] = As[(wm * 4 + t) * 64 + lane];
            bv[t] = Bs[(wn * 4 + t) * 64 + lane];
        }
        #pragma unroll
        for (int mt = 0; mt < 4; ++mt)
            #pragma unroll
            for (int nt = 0; nt < 4; ++nt)
                acc[mt][nt] = __builtin_amdgcn_mfma_f32_16x16x32_bf16(
                    av[mt], bv[nt], acc[mt][nt], 0, 0, 0);
        __syncthreads();
    }

    const int q = lane >> 4, m = lane & 15;
    #pragma unroll
    for (int mt = 0; mt < 4; ++mt) {
        #pragma unroll
        for (int nt = 0; nt < 4; ++nt) {
            const int col = n0 + wn * 64 + nt * 16 + m;
            const float bias = fc1_b[col];
            #pragma unroll
            for (int r = 0; r < 4; ++r) {
                const int row = m0 + wm * 64 + mt * 16 + q * 4 + r;
                float v = acc[mt][nt][r] + bias;
                float t = 1.f - 2.f / (__expf(2.f * v) + 1.f);
                h[(size_t)row * 4096 + col] = __float2bfloat16(t);
            }
        }
    }
}

// ---------------------------------------------------------------------------
// FC2 bf16 MFMA + fused softmax (unchanged, proven).
// ---------------------------------------------------------------------------
__global__ __launch_bounds__(256) void fc2_kernel(
    const __hip_bfloat16* __restrict__ h, const __hip_bfloat16* __restrict__ w2b,
    const float* __restrict__ fc2_b, float* __restrict__ out, int rowBase)
{
    __shared__ float part[4][32][64];
    const int tid  = threadIdx.x;
    const int lane = tid & 63;
    const int wv   = tid >> 6;
    const int rb = blockIdx.x * 32;
    const int m = lane & 15, q = lane >> 4;

    float4v acc[2][4] = {};
    const int kbase = wv * 1024;

    for (int s = 0; s < 32; ++s) {
        const int kk = kbase + s * 32 + q * 8;
        short8 av[2], bv[4];
        #pragma unroll
        for (int mt = 0; mt < 2; ++mt)
            av[mt] = *(const short8*)(h + (size_t)(rb + mt * 16 + m) * 4096 + kk);
        #pragma unroll
        for (int nt = 0; nt < 4; ++nt)
            bv[nt] = *(const short8*)(w2b + (size_t)(nt * 16 + m) * 4096 + kk);
        #pragma unroll
        for (int mt = 0; mt < 2; ++mt)
            #pragma unroll
            for (int nt = 0; nt < 4; ++nt)
                acc[mt][nt] = __builtin_amdgcn_mfma_f32_16x16x32_bf16(
                    av[mt], bv[nt], acc[mt][nt], 0, 0, 0);
    }

    #pragma unroll
    for (int mt = 0; mt < 2; ++mt)
        #pragma unroll
        for (int nt = 0; nt < 4; ++nt)
            #pragma unroll
            for (int r = 0; r < 4; ++r)
                part[wv][mt * 16 + q * 4 + r][nt * 16 + m] = acc[mt][nt][r];
    __syncthreads();

    #pragma unroll
    for (int t = 0; t < 8; ++t) {
        int idx = t * 256 + tid;
        int row = idx >> 6, col = idx & 63;
        float lg = part[0][row][col] + part[1][row][col]
                 + part[2][row][col] + part[3][row][col];
        part[0][row][col] = (col < 50) ? lg + fc2_b[col] : -1e30f;
    }
    __syncthreads();

    #pragma unroll
    for (int rr = 0; rr < 8; ++rr) {
        const int row = wv * 8 + rr;
        float v = part[0][row][lane];
        float mx = v;
        for (int off = 32; off > 0; off >>= 1) mx = fmaxf(mx, __shfl_xor(mx, off));
        float e = __expf(v - mx);
        float ssum = e;
        for (int off = 32; off > 0; off >>= 1) ssum += __shfl_xor(ssum, off);
        if (lane < 50)
            out[(size_t)(rowBase + rb + row) * 50 + lane] = e / ssum;
    }
}

// ---------------------------------------------------------------------------
extern "C" void kernel_launch(void* const* d_in, const int* in_sizes, int n_in,
                              void* d_out, int out_size, void* d_ws, size_t ws_size,
                              hipStream_t stream) {
    const int*   x        = (const int*)  d_in[0];
    const int*   wci      = (const int*)  d_in[1];
    const float* word_emb = (const float*)d_in[2];
    const float* char_emb = (const float*)d_in[3];
    const float* conv_w   = (const float*)d_in[4];
    const float* conv_b   = (const float*)d_in[5];
    const float* fc1_w    = (const float*)d_in[6];
    const float* fc1_b    = (const float*)d_in[7];
    const float* fc2_w    = (const float*)d_in[8];
    const float* fc2_b    = (const float*)d_in[9];
    float* out = (float*)d_out;

    char* ws = (char*)d_ws;
    __hip_bfloat16* ha  = (__hip_bfloat16*)ws;                                  // 8 MB
    __hip_bfloat16* wb  = (__hip_bfloat16*)(ws + ((size_t)8 << 20));            // 2 MB
    __hip_bfloat16* w2b = (__hip_bfloat16*)(ws + ((size_t)10 << 20));           // 0.5 MB
    __hip_bfloat16* h   = (__hip_bfloat16*)(ws + ((size_t)10 << 20) + ((size_t)512 << 10)); // 32 MB
    float*          gtp = (float*)(ws + ((size_t)42 << 20) + ((size_t)512 << 10));          // 78 KB

    wb_kernel<<<4096, 256, 0, stream>>>(fc1_w, wb);
    w2b_kernel<<<1024, 256, 0, stream>>>(fc2_w, w2b);
    gt_kernel<<<75, 256, 0, stream>>>(char_emb, conv_w, gtp);
    haPad_kernel<<<384, 256, 0, stream>>>(ha);
    conv_kernel<<<2560, 512, 0, stream>>>(x, wci, word_emb, conv_b, gtp, ha);
    for (int c = 0; c < 4; ++c) {
        const int rowBase = c * 4096;
        fc1_kernel<<<dim3(32, 32), 256, 0, stream>>>(ha, wb, fc1_b, h, rowBase);
        fc2_kernel<<<128, 256, 0, stream>>>(h, w2b, fc2_b, out, rowBase);
    }
}

// Round 10
// 382.200 us; speedup vs baseline: 1.3744x; 1.0109x over previous
//
#include <hip/hip_runtime.h>
#include <hip/hip_bf16.h>

// B=16384 W=5 L=20 E=50 V=100000 C=128 H=4096 O=50
// ha  = bf16 [16384][256] (K-padded 250->256)
// wb  = bf16 [4096][256]  (fc1_w as [N][K])
// w2b = bf16 [64][4096]   (fc2_w padded to 64 rows)
// h   = bf16 [4096][4096] per chunk
// gt  = fp32 [128][156]: gt[c*156 + k*52 + o] = sum_i char_emb[c][i]*conv_w[o][i][k]

typedef __attribute__((ext_vector_type(8))) short short8;
typedef __attribute__((ext_vector_type(4))) float float4v;

__device__ inline short bf16b(float f) {
    __hip_bfloat16 h = __float2bfloat16(f);
    return *reinterpret_cast<short*>(&h);
}
__device__ inline uint packbf2(float a, float b) {
    return (uint)(ushort)bf16b(a) | ((uint)(ushort)bf16b(b) << 16);
}

// ---------------------------------------------------------------------------
__global__ void wb_kernel(const float* __restrict__ fc1_w,
                          __hip_bfloat16* __restrict__ wb) {
    int idx = blockIdx.x * 256 + threadIdx.x;     // n*256 + k
    int n = idx >> 8, k = idx & 255;
    wb[idx] = __float2bfloat16(k < 250 ? fc1_w[n * 250 + k] : 0.f);
}

// ---------------------------------------------------------------------------
__global__ void w2b_kernel(const float* __restrict__ fc2_w,
                           __hip_bfloat16* __restrict__ w2b) {
    int idx = blockIdx.x * 256 + threadIdx.x;     // n*4096 + k
    int n = idx >> 12;
    w2b[idx] = __float2bfloat16(n < 50 ? fc2_w[idx] : 0.f);
}

// ---------------------------------------------------------------------------
// gt[c*156 + kk*52 + o] = sum_i char_emb[c*50+i] * conv_w[(o*50+i)*3+kk]
// ---------------------------------------------------------------------------
__global__ void gt_kernel(const float* __restrict__ char_emb,
                          const float* __restrict__ conv_w,
                          float* __restrict__ gt) {
    int idx = blockIdx.x * 256 + threadIdx.x;     // < 19200
    if (idx >= 19200) return;
    int c = idx / 150, rem = idx - c * 150;
    int kk = rem / 50, o = rem - kk * 50;
    const float* ce = char_emb + c * 50;
    const float* w  = conv_w + o * 150 + kk;
    float s = 0.f;
    #pragma unroll 10
    for (int i = 0; i < 50; ++i) s += ce[i] * w[i * 3];
    gt[c * 156 + kk * 52 + o] = s;
}

// ---------------------------------------------------------------------------
__global__ void haPad_kernel(__hip_bfloat16* __restrict__ ha) {
    int idx = blockIdx.x * 256 + threadIdx.x;     // b*6 + j
    int b = idx / 6, j = idx - b * 6;
    ha[b * 256 + 250 + j] = __float2bfloat16(0.f);
}

// ---------------------------------------------------------------------------
// conv via table lookup (unchanged, proven R7). Block = 512 thr = 32 words.
// ---------------------------------------------------------------------------
__global__ __launch_bounds__(512) void conv_kernel(
    const int* __restrict__ x, const int* __restrict__ wci,
    const float* __restrict__ word_emb, const float* __restrict__ conv_b,
    const float* __restrict__ gt, __hip_bfloat16* __restrict__ ha)
{
    __shared__ float Gs[19968];       // 79,872 B
    __shared__ uint  cpack[160];
    __shared__ int   xs[32];

    const int tid = threadIdx.x;
    const int gw0 = blockIdx.x * 32;

    int xr = 0;
    if (tid < 32) xr = x[gw0 + tid];

    #pragma unroll
    for (int t = 0; t < 39; ++t)
        Gs[t * 512 + tid] = gt[t * 512 + tid];

    if (tid < 32) {
        const int* crow = wci + xr * 20;
        int cid[20];
        #pragma unroll
        for (int p = 0; p < 20; ++p) cid[p] = crow[p];
        #pragma unroll
        for (int u = 0; u < 5; ++u)
            cpack[tid * 5 + u] = (uint)cid[u * 4] | ((uint)cid[u * 4 + 1] << 8)
                               | ((uint)cid[u * 4 + 2] << 16) | ((uint)cid[u * 4 + 3] << 24);
        xs[tid] = xr;
    }
    __syncthreads();

    const int lane = tid & 63;
    const int wv   = tid >> 6;
    const int t    = lane & 15;
    const int w    = lane >> 4;
    const int tc   = (t < 13) ? t : 12;
    const int widx = wv * 4 + w;

    uint cw[5];
    #pragma unroll
    for (int u = 0; u < 5; ++u) cw[u] = cpack[widx * 5 + u];
    int ca[20];
    #pragma unroll
    for (int p = 0; p < 20; ++p)
        ca[p] = (int)((cw[p >> 2] >> ((p & 3) * 8)) & 0xFF) * 156;

    const int tc4 = tc * 4;
    float4 mx;
    {
        float4 v = *(const float4*)&Gs[ca[0] + 52 + tc4];
        float4 u = *(const float4*)&Gs[ca[1] + 104 + tc4];
        mx.x = v.x + u.x; mx.y = v.y + u.y; mx.z = v.z + u.z; mx.w = v.w + u.w;
    }
    #pragma unroll
    for (int l = 1; l < 19; ++l) {
        float4 v = *(const float4*)&Gs[ca[l] + 52 + tc4];
        float4 a = *(const float4*)&Gs[ca[l - 1] + tc4];
        float4 b = *(const float4*)&Gs[ca[l + 1] + 104 + tc4];
        float vx = v.x + a.x + b.x, vy = v.y + a.y + b.y;
        float vz = v.z + a.z + b.z, vw = v.w + a.w + b.w;
        mx.x = fmaxf(mx.x, vx); mx.y = fmaxf(mx.y, vy);
        mx.z = fmaxf(mx.z, vz); mx.w = fmaxf(mx.w, vw);
    }
    {
        float4 v = *(const float4*)&Gs[ca[19] + 52 + tc4];
        float4 a = *(const float4*)&Gs[ca[18] + tc4];
        mx.x = fmaxf(mx.x, v.x + a.x); mx.y = fmaxf(mx.y, v.y + a.y);
        mx.z = fmaxf(mx.z, v.z + a.z); mx.w = fmaxf(mx.w, v.w + a.w);
    }

    const int xid = xs[widx];
    const float* wer = word_emb + (size_t)xid * 50 + tc4;
    float2 wea = *(const float2*)wer;
    float2 web = make_float2(0.f, 0.f);
    float2 cba = *(const float2*)(conv_b + tc4);
    float2 cbb = make_float2(0.f, 0.f);
    if (tc < 12) {
        web = *(const float2*)(wer + 2);
        cbb = *(const float2*)(conv_b + tc4 + 2);
    }
    const int gw = gw0 + widx, b = gw / 5, wp = gw - b * 5;
    __hip_bfloat16* dst = ha + b * 256 + wp * 50 + tc4;
    uint lo = packbf2(mx.x + cba.x + wea.x, mx.y + cba.y + wea.y);
    if (t < 12) {
        uint hi = packbf2(mx.z + cbb.x + web.x, mx.w + cbb.y + web.y);
        *(uint*)dst = lo;
        *((uint*)dst + 1) = hi;
    } else if (t == 12) {
        *(uint*)dst = lo;
    }
}

// ---------------------------------------------------------------------------
// FC1 bf16 MFMA: 128x128 tile, 4 waves 2x2, BK=64 via per-lane short8 staging
// (4 stores/thread). 32 MFMA per barrier-pair. <-- THE ONE unproven change.
// ---------------------------------------------------------------------------
__global__ __launch_bounds__(256) void fc1_kernel(
    const __hip_bfloat16* __restrict__ ha, const __hip_bfloat16* __restrict__ wb,
    const float* __restrict__ fc1_b, __hip_bfloat16* __restrict__ h, int rowBase)
{
    __shared__ short8 As[1024];   // [(ks*8+mt)*64 + lane]  16 KB
    __shared__ short8 Bs[1024];   // 16 KB
    const int tid  = threadIdx.x;
    const int lane = tid & 63;
    const int wv   = tid >> 6;
    const int wm = wv >> 1, wn = wv & 1;
    const int m0 = blockIdx.x * 128;
    const int n0 = blockIdx.y * 128;

    float4v acc[4][4] = {};

    for (int kt = 0; kt < 4; ++kt) {
        const int k0 = kt * 64;
        #pragma unroll
        for (int s = 0; s < 4; ++s) {
            const int seg = s * 256 + tid;        // 0..1023
            const int grp = seg >> 6;             // ks*8 + mt
            const int ks = grp >> 3, mt = grp & 7;
            const int l = seg & 63;
            const int q = l >> 4, mm = l & 15;
            As[seg] = *(const short8*)(ha + (size_t)(rowBase + m0 + mt * 16 + mm) * 256
                                          + k0 + ks * 32 + q * 8);
            Bs[seg] = *(const short8*)(wb + (size_t)(n0 + mt * 16 + mm) * 256
                                          + k0 + ks * 32 + q * 8);
        }
        __syncthreads();
        #pragma unroll
        for (int ks = 0; ks < 2; ++ks) {
            short8 av[4], bv[4];
            #pragma unroll
            for (int t = 0; t < 4; ++t) {
                av[t] = As[(ks * 8 + wm * 4 + t) * 64 + lane];
                bv[t] = Bs[(ks * 8 + wn * 4 + t) * 64 + lane];
            }
            #pragma unroll
            for (int mt = 0; mt < 4; ++mt)
                #pragma unroll
                for (int nt = 0; nt < 4; ++nt)
                    acc[mt][nt] = __builtin_amdgcn_mfma_f32_16x16x32_bf16(
                        av[mt], bv[nt], acc[mt][nt], 0, 0, 0);
        }
        __syncthreads();
    }

    const int q = lane >> 4, m = lane & 15;
    #pragma unroll
    for (int mt = 0; mt < 4; ++mt) {
        #pragma unroll
        for (int nt = 0; nt < 4; ++nt) {
            const int col = n0 + wn * 64 + nt * 16 + m;
            const float bias = fc1_b[col];
            #pragma unroll
            for (int r = 0; r < 4; ++r) {
                const int row = m0 + wm * 64 + mt * 16 + q * 4 + r;
                float v = acc[mt][nt][r] + bias;
                float t = 1.f - 2.f / (__expf(2.f * v) + 1.f);
                h[(size_t)row * 4096 + col] = __float2bfloat16(t);
            }
        }
    }
}

// ---------------------------------------------------------------------------
// FC2 bf16 MFMA + fused softmax (VERBATIM proven R3/R5/R6/R7 32-row version).
// ---------------------------------------------------------------------------
__global__ __launch_bounds__(256) void fc2_kernel(
    const __hip_bfloat16* __restrict__ h, const __hip_bfloat16* __restrict__ w2b,
    const float* __restrict__ fc2_b, float* __restrict__ out, int rowBase)
{
    __shared__ float part[4][32][64];
    const int tid  = threadIdx.x;
    const int lane = tid & 63;
    const int wv   = tid >> 6;
    const int rb = blockIdx.x * 32;
    const int m = lane & 15, q = lane >> 4;

    float4v acc[2][4] = {};
    const int kbase = wv * 1024;

    for (int s = 0; s < 32; ++s) {
        const int kk = kbase + s * 32 + q * 8;
        short8 av[2], bv[4];
        #pragma unroll
        for (int mt = 0; mt < 2; ++mt)
            av[mt] = *(const short8*)(h + (size_t)(rb + mt * 16 + m) * 4096 + kk);
        #pragma unroll
        for (int nt = 0; nt < 4; ++nt)
            bv[nt] = *(const short8*)(w2b + (size_t)(nt * 16 + m) * 4096 + kk);
        #pragma unroll
        for (int mt = 0; mt < 2; ++mt)
            #pragma unroll
            for (int nt = 0; nt < 4; ++nt)
                acc[mt][nt] = __builtin_amdgcn_mfma_f32_16x16x32_bf16(
                    av[mt], bv[nt], acc[mt][nt], 0, 0, 0);
    }

    #pragma unroll
    for (int mt = 0; mt < 2; ++mt)
        #pragma unroll
        for (int nt = 0; nt < 4; ++nt)
            #pragma unroll
            for (int r = 0; r < 4; ++r)
                part[wv][mt * 16 + q * 4 + r][nt * 16 + m] = acc[mt][nt][r];
    __syncthreads();

    #pragma unroll
    for (int t = 0; t < 8; ++t) {
        int idx = t * 256 + tid;
        int row = idx >> 6, col = idx & 63;
        float lg = part[0][row][col] + part[1][row][col]
                 + part[2][row][col] + part[3][row][col];
        part[0][row][col] = (col < 50) ? lg + fc2_b[col] : -1e30f;
    }
    __syncthreads();

    #pragma unroll
    for (int rr = 0; rr < 8; ++rr) {
        const int row = wv * 8 + rr;
        float v = part[0][row][lane];
        float mx = v;
        for (int off = 32; off > 0; off >>= 1) mx = fmaxf(mx, __shfl_xor(mx, off));
        float e = __expf(v - mx);
        float ssum = e;
        for (int off = 32; off > 0; off >>= 1) ssum += __shfl_xor(ssum, off);
        if (lane < 50)
            out[(size_t)(rowBase + rb + row) * 50 + lane] = e / ssum;
    }
}

// ---------------------------------------------------------------------------
extern "C" void kernel_launch(void* const* d_in, const int* in_sizes, int n_in,
                              void* d_out, int out_size, void* d_ws, size_t ws_size,
                              hipStream_t stream) {
    const int*   x        = (const int*)  d_in[0];
    const int*   wci      = (const int*)  d_in[1];
    const float* word_emb = (const float*)d_in[2];
    const float* char_emb = (const float*)d_in[3];
    const float* conv_w   = (const float*)d_in[4];
    const float* conv_b   = (const float*)d_in[5];
    const float* fc1_w    = (const float*)d_in[6];
    const float* fc1_b    = (const float*)d_in[7];
    const float* fc2_w    = (const float*)d_in[8];
    const float* fc2_b    = (const float*)d_in[9];
    float* out = (float*)d_out;

    char* ws = (char*)d_ws;
    __hip_bfloat16* ha  = (__hip_bfloat16*)ws;                                  // 8 MB
    __hip_bfloat16* wb  = (__hip_bfloat16*)(ws + ((size_t)8 << 20));            // 2 MB
    __hip_bfloat16* w2b = (__hip_bfloat16*)(ws + ((size_t)10 << 20));           // 0.5 MB
    __hip_bfloat16* h   = (__hip_bfloat16*)(ws + ((size_t)10 << 20) + ((size_t)512 << 10)); // 32 MB
    float*          gtp = (float*)(ws + ((size_t)42 << 20) + ((size_t)512 << 10));          // 78 KB

    wb_kernel<<<4096, 256, 0, stream>>>(fc1_w, wb);
    w2b_kernel<<<1024, 256, 0, stream>>>(fc2_w, w2b);
    gt_kernel<<<75, 256, 0, stream>>>(char_emb, conv_w, gtp);
    haPad_kernel<<<384, 256, 0, stream>>>(ha);
    conv_kernel<<<2560, 512, 0, stream>>>(x, wci, word_emb, conv_b, gtp, ha);
    for (int c = 0; c < 4; ++c) {
        const int rowBase = c * 4096;
        fc1_kernel<<<dim3(32, 32), 256, 0, stream>>>(ha, wb, fc1_b, h, rowBase);
        fc2_kernel<<<128, 256, 0, stream>>>(h, w2b, fc2_b, out, rowBase);
    }
}

// Round 11
// 283.780 us; speedup vs baseline: 1.8511x; 1.3468x over previous
//
#include <hip/hip_runtime.h>
#include <hip/hip_bf16.h>

// B=16384 W=5 L=20 E=50 V=100000 C=128 H=4096 O=50
// ha  = bf16 [16384][256] (K-padded 250->256)        ws+0      (8 MB)
// wb  = bf16 [4096][256]  (fc1_w as [N][K])          ws+8M     (2 MB)
// w2b = bf16 [64][4096]   (fc2_w padded to 64 rows)  ws+10M    (0.5 MB)
// h   = bf16 [16384][4096] FULL batch                ws+16M    (128 MB)
// gt  = fp32 [128][156]                              ws+144M   (78 KB)
// ws >= 256 MiB (harness poison fill = 262144 KB).

typedef __attribute__((ext_vector_type(8))) short short8;
typedef __attribute__((ext_vector_type(4))) float float4v;

__device__ inline short bf16b(float f) {
    __hip_bfloat16 h = __float2bfloat16(f);
    return *reinterpret_cast<short*>(&h);
}
__device__ inline uint packbf2(float a, float b) {
    return (uint)(ushort)bf16b(a) | ((uint)(ushort)bf16b(b) << 16);
}

// ---------------------------------------------------------------------------
__global__ void wb_kernel(const float* __restrict__ fc1_w,
                          __hip_bfloat16* __restrict__ wb) {
    int idx = blockIdx.x * 256 + threadIdx.x;     // n*256 + k
    int n = idx >> 8, k = idx & 255;
    wb[idx] = __float2bfloat16(k < 250 ? fc1_w[n * 250 + k] : 0.f);
}

// ---------------------------------------------------------------------------
__global__ void w2b_kernel(const float* __restrict__ fc2_w,
                           __hip_bfloat16* __restrict__ w2b) {
    int idx = blockIdx.x * 256 + threadIdx.x;     // n*4096 + k
    int n = idx >> 12;
    w2b[idx] = __float2bfloat16(n < 50 ? fc2_w[idx] : 0.f);
}

// ---------------------------------------------------------------------------
// gt[c*156 + kk*52 + o] = sum_i char_emb[c*50+i] * conv_w[(o*50+i)*3+kk]
// ---------------------------------------------------------------------------
__global__ void gt_kernel(const float* __restrict__ char_emb,
                          const float* __restrict__ conv_w,
                          float* __restrict__ gt) {
    int idx = blockIdx.x * 256 + threadIdx.x;     // < 19200
    if (idx >= 19200) return;
    int c = idx / 150, rem = idx - c * 150;
    int kk = rem / 50, o = rem - kk * 50;
    const float* ce = char_emb + c * 50;
    const float* w  = conv_w + o * 150 + kk;
    float s = 0.f;
    #pragma unroll 10
    for (int i = 0; i < 50; ++i) s += ce[i] * w[i * 3];
    gt[c * 156 + kk * 52 + o] = s;
}

// ---------------------------------------------------------------------------
__global__ void haPad_kernel(__hip_bfloat16* __restrict__ ha) {
    int idx = blockIdx.x * 256 + threadIdx.x;     // b*6 + j
    int b = idx / 6, j = idx - b * 6;
    ha[b * 256 + 250 + j] = __float2bfloat16(0.f);
}

// ---------------------------------------------------------------------------
// conv via table lookup (unchanged, proven R7). Block = 512 thr = 32 words.
// ---------------------------------------------------------------------------
__global__ __launch_bounds__(512) void conv_kernel(
    const int* __restrict__ x, const int* __restrict__ wci,
    const float* __restrict__ word_emb, const float* __restrict__ conv_b,
    const float* __restrict__ gt, __hip_bfloat16* __restrict__ ha)
{
    __shared__ float Gs[19968];       // 79,872 B
    __shared__ uint  cpack[160];
    __shared__ int   xs[32];

    const int tid = threadIdx.x;
    const int gw0 = blockIdx.x * 32;

    int xr = 0;
    if (tid < 32) xr = x[gw0 + tid];

    #pragma unroll
    for (int t = 0; t < 39; ++t)
        Gs[t * 512 + tid] = gt[t * 512 + tid];

    if (tid < 32) {
        const int* crow = wci + xr * 20;
        int cid[20];
        #pragma unroll
        for (int p = 0; p < 20; ++p) cid[p] = crow[p];
        #pragma unroll
        for (int u = 0; u < 5; ++u)
            cpack[tid * 5 + u] = (uint)cid[u * 4] | ((uint)cid[u * 4 + 1] << 8)
                               | ((uint)cid[u * 4 + 2] << 16) | ((uint)cid[u * 4 + 3] << 24);
        xs[tid] = xr;
    }
    __syncthreads();

    const int lane = tid & 63;
    const int wv   = tid >> 6;
    const int t    = lane & 15;
    const int w    = lane >> 4;
    const int tc   = (t < 13) ? t : 12;
    const int widx = wv * 4 + w;

    uint cw[5];
    #pragma unroll
    for (int u = 0; u < 5; ++u) cw[u] = cpack[widx * 5 + u];
    int ca[20];
    #pragma unroll
    for (int p = 0; p < 20; ++p)
        ca[p] = (int)((cw[p >> 2] >> ((p & 3) * 8)) & 0xFF) * 156;

    const int tc4 = tc * 4;
    float4 mx;
    {
        float4 v = *(const float4*)&Gs[ca[0] + 52 + tc4];
        float4 u = *(const float4*)&Gs[ca[1] + 104 + tc4];
        mx.x = v.x + u.x; mx.y = v.y + u.y; mx.z = v.z + u.z; mx.w = v.w + u.w;
    }
    #pragma unroll
    for (int l = 1; l < 19; ++l) {
        float4 v = *(const float4*)&Gs[ca[l] + 52 + tc4];
        float4 a = *(const float4*)&Gs[ca[l - 1] + tc4];
        float4 b = *(const float4*)&Gs[ca[l + 1] + 104 + tc4];
        float vx = v.x + a.x + b.x, vy = v.y + a.y + b.y;
        float vz = v.z + a.z + b.z, vw = v.w + a.w + b.w;
        mx.x = fmaxf(mx.x, vx); mx.y = fmaxf(mx.y, vy);
        mx.z = fmaxf(mx.z, vz); mx.w = fmaxf(mx.w, vw);
    }
    {
        float4 v = *(const float4*)&Gs[ca[19] + 52 + tc4];
        float4 a = *(const float4*)&Gs[ca[18] + tc4];
        mx.x = fmaxf(mx.x, v.x + a.x); mx.y = fmaxf(mx.y, v.y + a.y);
        mx.z = fmaxf(mx.z, v.z + a.z); mx.w = fmaxf(mx.w, v.w + a.w);
    }

    const int xid = xs[widx];
    const float* wer = word_emb + (size_t)xid * 50 + tc4;
    float2 wea = *(const float2*)wer;
    float2 web = make_float2(0.f, 0.f);
    float2 cba = *(const float2*)(conv_b + tc4);
    float2 cbb = make_float2(0.f, 0.f);
    if (tc < 12) {
        web = *(const float2*)(wer + 2);
        cbb = *(const float2*)(conv_b + tc4 + 2);
    }
    const int gw = gw0 + widx, b = gw / 5, wp = gw - b * 5;
    __hip_bfloat16* dst = ha + b * 256 + wp * 50 + tc4;
    uint lo = packbf2(mx.x + cba.x + wea.x, mx.y + cba.y + wea.y);
    if (t < 12) {
        uint hi = packbf2(mx.z + cbb.x + web.x, mx.w + cbb.y + web.y);
        *(uint*)dst = lo;
        *((uint*)dst + 1) = hi;
    } else if (t == 12) {
        *(uint*)dst = lo;
    }
}

// ---------------------------------------------------------------------------
// FC1 bf16 MFMA (R10-proven body, de-chunked): 128x128 tile, 4 waves 2x2,
// BK=64 per-lane short8 staging. Grid dim3(128, 32) covers all 16384 rows.
// ---------------------------------------------------------------------------
__global__ __launch_bounds__(256) void fc1_kernel(
    const __hip_bfloat16* __restrict__ ha, const __hip_bfloat16* __restrict__ wb,
    const float* __restrict__ fc1_b, __hip_bfloat16* __restrict__ h)
{
    __shared__ short8 As[1024];   // [(ks*8+mt)*64 + lane]  16 KB
    __shared__ short8 Bs[1024];   // 16 KB
    const int tid  = threadIdx.x;
    const int lane = tid & 63;
    const int wv   = tid >> 6;
    const int wm = wv >> 1, wn = wv & 1;
    const int m0 = blockIdx.x * 128;
    const int n0 = blockIdx.y * 128;

    float4v acc[4][4] = {};

    for (int kt = 0; kt < 4; ++kt) {
        const int k0 = kt * 64;
        #pragma unroll
        for (int s = 0; s < 4; ++s) {
            const int seg = s * 256 + tid;        // 0..1023
            const int grp = seg >> 6;             // ks*8 + mt
            const int ks = grp >> 3, mt = grp & 7;
            const int l = seg & 63;
            const int q = l >> 4, mm = l & 15;
            As[seg] = *(const short8*)(ha + (size_t)(m0 + mt * 16 + mm) * 256
                                          + k0 + ks * 32 + q * 8);
            Bs[seg] = *(const short8*)(wb + (size_t)(n0 + mt * 16 + mm) * 256
                                          + k0 + ks * 32 + q * 8);
        }
        __syncthreads();
        #pragma unroll
        for (int ks = 0; ks < 2; ++ks) {
            short8 av[4], bv[4];
            #pragma unroll
            for (int t = 0; t < 4; ++t) {
                av[t] = As[(ks * 8 + wm * 4 + t) * 64 + lane];
                bv[t] = Bs[(ks * 8 + wn * 4 + t) * 64 + lane];
            }
            #pragma unroll
            for (int mt = 0; mt < 4; ++mt)
                #pragma unroll
                for (int nt = 0; nt < 4; ++nt)
                    acc[mt][nt] = __builtin_amdgcn_mfma_f32_16x16x32_bf16(
                        av[mt], bv[nt], acc[mt][nt], 0, 0, 0);
        }
        __syncthreads();
    }

    const int q = lane >> 4, m = lane & 15;
    #pragma unroll
    for (int mt = 0; mt < 4; ++mt) {
        #pragma unroll
        for (int nt = 0; nt < 4; ++nt) {
            const int col = n0 + wn * 64 + nt * 16 + m;
            const float bias = fc1_b[col];
            #pragma unroll
            for (int r = 0; r < 4; ++r) {
                const int row = m0 + wm * 64 + mt * 16 + q * 4 + r;
                float v = acc[mt][nt][r] + bias;
                float t = 1.f - 2.f / (__expf(2.f * v) + 1.f);
                h[(size_t)row * 4096 + col] = __float2bfloat16(t);
            }
        }
    }
}

// ---------------------------------------------------------------------------
// FC2 bf16 MFMA + fused softmax (proven 32-row body, de-chunked):
// 512 blocks x 32 rows = 16384 rows, 2 blocks/CU.
// ---------------------------------------------------------------------------
__global__ __launch_bounds__(256) void fc2_kernel(
    const __hip_bfloat16* __restrict__ h, const __hip_bfloat16* __restrict__ w2b,
    const float* __restrict__ fc2_b, float* __restrict__ out)
{
    __shared__ float part[4][32][64];
    const int tid  = threadIdx.x;
    const int lane = tid & 63;
    const int wv   = tid >> 6;
    const int rb = blockIdx.x * 32;     // global row base
    const int m = lane & 15, q = lane >> 4;

    float4v acc[2][4] = {};
    const int kbase = wv * 1024;

    for (int s = 0; s < 32; ++s) {
        const int kk = kbase + s * 32 + q * 8;
        short8 av[2], bv[4];
        #pragma unroll
        for (int mt = 0; mt < 2; ++mt)
            av[mt] = *(const short8*)(h + (size_t)(rb + mt * 16 + m) * 4096 + kk);
        #pragma unroll
        for (int nt = 0; nt < 4; ++nt)
            bv[nt] = *(const short8*)(w2b + (size_t)(nt * 16 + m) * 4096 + kk);
        #pragma unroll
        for (int mt = 0; mt < 2; ++mt)
            #pragma unroll
            for (int nt = 0; nt < 4; ++nt)
                acc[mt][nt] = __builtin_amdgcn_mfma_f32_16x16x32_bf16(
                    av[mt], bv[nt], acc[mt][nt], 0, 0, 0);
    }

    #pragma unroll
    for (int mt = 0; mt < 2; ++mt)
        #pragma unroll
        for (int nt = 0; nt < 4; ++nt)
            #pragma unroll
            for (int r = 0; r < 4; ++r)
                part[wv][mt * 16 + q * 4 + r][nt * 16 + m] = acc[mt][nt][r];
    __syncthreads();

    #pragma unroll
    for (int t = 0; t < 8; ++t) {
        int idx = t * 256 + tid;
        int row = idx >> 6, col = idx & 63;
        float lg = part[0][row][col] + part[1][row][col]
                 + part[2][row][col] + part[3][row][col];
        part[0][row][col] = (col < 50) ? lg + fc2_b[col] : -1e30f;
    }
    __syncthreads();

    #pragma unroll
    for (int rr = 0; rr < 8; ++rr) {
        const int row = wv * 8 + rr;
        float v = part[0][row][lane];
        float mx = v;
        for (int off = 32; off > 0; off >>= 1) mx = fmaxf(mx, __shfl_xor(mx, off));
        float e = __expf(v - mx);
        float ssum = e;
        for (int off = 32; off > 0; off >>= 1) ssum += __shfl_xor(ssum, off);
        if (lane < 50)
            out[(size_t)(rb + row) * 50 + lane] = e / ssum;
    }
}

// ---------------------------------------------------------------------------
extern "C" void kernel_launch(void* const* d_in, const int* in_sizes, int n_in,
                              void* d_out, int out_size, void* d_ws, size_t ws_size,
                              hipStream_t stream) {
    const int*   x        = (const int*)  d_in[0];
    const int*   wci      = (const int*)  d_in[1];
    const float* word_emb = (const float*)d_in[2];
    const float* char_emb = (const float*)d_in[3];
    const float* conv_w   = (const float*)d_in[4];
    const float* conv_b   = (const float*)d_in[5];
    const float* fc1_w    = (const float*)d_in[6];
    const float* fc1_b    = (const float*)d_in[7];
    const float* fc2_w    = (const float*)d_in[8];
    const float* fc2_b    = (const float*)d_in[9];
    float* out = (float*)d_out;

    char* ws = (char*)d_ws;
    __hip_bfloat16* ha  = (__hip_bfloat16*)ws;                          // 8 MB
    __hip_bfloat16* wb  = (__hip_bfloat16*)(ws + ((size_t)8  << 20));   // 2 MB
    __hip_bfloat16* w2b = (__hip_bfloat16*)(ws + ((size_t)10 << 20));   // 0.5 MB
    __hip_bfloat16* h   = (__hip_bfloat16*)(ws + ((size_t)16 << 20));   // 128 MB
    float*          gtp = (float*)(ws + ((size_t)144 << 20));           // 78 KB

    wb_kernel<<<4096, 256, 0, stream>>>(fc1_w, wb);
    w2b_kernel<<<1024, 256, 0, stream>>>(fc2_w, w2b);
    gt_kernel<<<75, 256, 0, stream>>>(char_emb, conv_w, gtp);
    haPad_kernel<<<384, 256, 0, stream>>>(ha);
    conv_kernel<<<2560, 512, 0, stream>>>(x, wci, word_emb, conv_b, gtp, ha);
    fc1_kernel<<<dim3(128, 32), 256, 0, stream>>>(ha, wb, fc1_b, h);
    fc2_kernel<<<512, 256, 0, stream>>>(h, w2b, fc2_b, out);
}